// Round 13
// baseline (425.087 us; speedup 1.0000x reference)
//
#include <hip/hip_runtime.h>
#include <math.h>

#define NPOINTS (1 << 21)
#define LVL 16
#define TSIZE (1 << 19)
#define TMASK (TSIZE - 1)
#define PRIME2 2654435761u

// Bucket grid: 256 x 256 = 2^16 buckets, ~32 pts each, capacity 80.
#define BRES 256
#define NBKT 65536
#define CAP 80

typedef float f32x2 __attribute__((ext_vector_type(2)));
typedef float f32x4 __attribute__((ext_vector_type(4)));

struct ResArr {
    int   n[LVL];
    float fn[LVL];
};

__device__ __forceinline__ unsigned part1by1(unsigned v) {
    v &= 0xFFFFu;
    v = (v | (v << 8)) & 0x00FF00FFu;
    v = (v | (v << 4)) & 0x0F0F0F0Fu;
    v = (v | (v << 2)) & 0x33333333u;
    v = (v | (v << 1)) & 0x55555555u;
    return v;
}

__device__ __forceinline__ unsigned bucket_key(f32x2 pt) {
    int kx = (int)(pt.x * (float)BRES);
    int ky = (int)(pt.y * (float)BRES);
    kx = min(max(kx, 0), BRES - 1);
    ky = min(max(ky, 0), BRES - 1);
    return (part1by1((unsigned)ky) << 1) | part1by1((unsigned)kx);  // Morton
}

// Plain 4-gather bilinear lookup (bit-identical to reference math).
__device__ __forceinline__ f32x2 level_feat(const f32x2* __restrict__ tables,
                                            int l, int N, float fN, f32x2 pt)
{
    float sx = pt.x * fN;
    float sy = pt.y * fN;
    float fx = floorf(sx);
    float fy = floorf(sy);
    float wx = sx - fx;
    float wy = sy - fy;
    int ix = (int)fx;
    int iy = (int)fy;

    int cx0 = (ix     >= N) ? ix - N     : ix;
    int cx1 = (ix + 1 >= N) ? ix + 1 - N : ix + 1;
    int cy0 = (iy     >= N) ? iy - N     : iy;
    int cy1 = (iy + 1 >= N) ? iy + 1 - N : iy + 1;

    unsigned hy0 = (unsigned)cy0 * PRIME2;
    unsigned hy1 = (unsigned)cy1 * PRIME2;

    const f32x2* tbl = tables + (size_t)l * TSIZE;
    f32x2 c00 = tbl[(int)(((unsigned)cx0 ^ hy0) & TMASK)];
    f32x2 c10 = tbl[(int)(((unsigned)cx1 ^ hy0) & TMASK)];
    f32x2 c01 = tbl[(int)(((unsigned)cx0 ^ hy1) & TMASK)];
    f32x2 c11 = tbl[(int)(((unsigned)cx1 ^ hy1) & TMASK)];

    float omx = 1.0f - wx, omy = 1.0f - wy;
    float f0x = c00.x * omx + c10.x * wx;
    float f0y = c00.y * omx + c10.y * wx;
    float f1x = c01.x * omx + c11.x * wx;
    float f1y = c01.y * omx + c11.y * wx;

    f32x2 r;
    r.x = f0x * omy + f1x * wy;
    r.y = f0y * omy + f1y * wy;
    return r;
}

__device__ __forceinline__ void point_out(const f32x2* __restrict__ tables,
                                          const ResArr& res, f32x2 pt,
                                          f32x4* __restrict__ o)
{
    #pragma unroll
    for (int hb = 0; hb < 2; ++hb) {          // 8 levels = one 64B out line
        f32x2 r[8];
        #pragma unroll
        for (int j = 0; j < 8; ++j) {
            int l = hb * 8 + j;
            r[j] = level_feat(tables, l, res.n[l], res.fn[l], pt);
        }
        #pragma unroll
        for (int q = 0; q < 4; ++q) {
            f32x4 v = { r[2 * q].x, r[2 * q].y, r[2 * q + 1].x, r[2 * q + 1].y };
            o[hb * 4 + q] = v;
        }
    }
}

// ---- Bucket assignment: ONE kernel, no hist/scan. Packed 16B slot {x,y,idx}
// = one random line-RMW per point (R11 scatter did two). Overflow (P~1e-12
// per bucket at CAP=80) goes to a guarded list drained after main.
__global__ __launch_bounds__(256) void bucket_kernel(
    const f32x2* __restrict__ xy,
    unsigned* __restrict__ cnt,
    f32x4* __restrict__ slots,
    unsigned* __restrict__ ovf_cnt,
    unsigned* __restrict__ ovf)
{
    int p = blockIdx.x * 256 + threadIdx.x;
    f32x2 pt = __builtin_nontemporal_load(&xy[p]);
    unsigned key = bucket_key(pt);
    unsigned pos = atomicAdd(&cnt[key], 1u);
    if (pos < CAP) {
        f32x4 s = { pt.x, pt.y, __uint_as_float((unsigned)p), 0.0f };
        __builtin_nontemporal_store(s, &slots[(size_t)key * CAP + pos]);
    } else {
        unsigned q = atomicAdd(ovf_cnt, 1u);
        ovf[q] = (unsigned)p;
    }
}

// ---- Main: one wave per bucket (4 buckets per 256-block). Wave lanes share
// a 1/256-square extent -> levels <=12 collapse to ~4 lines/instruction via
// TCP same-line merging. XCD-chunked swizzle: each XCD owns a contiguous
// Morton region (~4MB hot table slice ~ its L2).
__global__ __launch_bounds__(256) void main_kernel(
    const unsigned* __restrict__ cnt,
    const f32x4* __restrict__ slots,
    const f32x2* __restrict__ tables,
    f32x4* __restrict__ out,
    ResArr res)
{
    int bid  = blockIdx.x;                        // 0..16383
    int swz  = (bid & 7) * (NBKT / 4 / 8) + (bid >> 3);
    int b    = swz * 4 + (threadIdx.x >> 6);      // bucket 0..65535
    int lane = threadIdx.x & 63;

    unsigned n = cnt[b];
    if (n > CAP) n = CAP;
    if (lane >= (int)n) return;

    f32x4 s = __builtin_nontemporal_load(&slots[(size_t)b * CAP + lane]);
    f32x2 pt = { s.x, s.y };
    unsigned op = __float_as_uint(s.z);

    point_out(tables, res, pt, out + (size_t)op * 8);
}

// ---- Overflow drain (normally 0 iterations).
__global__ __launch_bounds__(256) void ovf_kernel(
    const unsigned* __restrict__ ovf_cnt,
    const unsigned* __restrict__ ovf,
    const f32x2* __restrict__ xy,
    const f32x2* __restrict__ tables,
    f32x4* __restrict__ out,
    ResArr res)
{
    unsigned n = *ovf_cnt;
    for (unsigned i = blockIdx.x * 256 + threadIdx.x; i < n; i += gridDim.x * 256) {
        unsigned p = ovf[i];
        f32x2 pt = xy[p];
        point_out(tables, res, pt, out + (size_t)p * 8);
    }
}

// ---- Fallback (ws too small): single-pass kernel (~433 us).
__global__ __launch_bounds__(256, 6) void hashgrid2d_fallback(
    const f32x2* __restrict__ xy,
    const f32x2* __restrict__ tables,
    f32x4* __restrict__ out,
    ResArr res)
{
    __shared__ f32x4 lds[256 * 5];

    int tid = threadIdx.x;
    int p   = blockIdx.x * 256 + tid;

    f32x2 pt = __builtin_nontemporal_load(&xy[p]);
    size_t base = (size_t)blockIdx.x * 2048;

    #pragma unroll
    for (int b = 0; b < 2; ++b) {
        #pragma unroll
        for (int q = 0; q < 4; ++q) {
            float f[4];
            #pragma unroll
            for (int j = 0; j < 2; ++j) {
                int l = b * 8 + q * 2 + j;
                f32x2 r = level_feat(tables, l, res.n[l], res.fn[l], pt);
                f[j * 2 + 0] = r.x;
                f[j * 2 + 1] = r.y;
            }
            f32x4 v = { f[0], f[1], f[2], f[3] };
            lds[tid * 5 + q] = v;
        }
        __syncthreads();
        #pragma unroll
        for (int i = 0; i < 4; ++i) {
            int e  = i * 256 + tid;
            int pp = e >> 2;
            int q  = e & 3;
            f32x4 v = lds[pp * 5 + q];
            __builtin_nontemporal_store(v, &out[base + pp * 8 + b * 4 + q]);
        }
        __syncthreads();
    }
}

extern "C" void kernel_launch(void* const* d_in, const int* in_sizes, int n_in,
                              void* d_out, int out_size, void* d_ws, size_t ws_size,
                              hipStream_t stream) {
    const f32x2* xy     = (const f32x2*)d_in[0];
    const f32x2* tables = (const f32x2*)d_in[1];
    f32x4* out = (f32x4*)d_out;

    ResArr res;
    double b = pow(2048.0 / 16.0, 1.0 / 15.0);
    for (int l = 0; l < LVL; ++l) {
        int N = (int)llround(16.0 * pow(b, (double)l));
        res.n[l]  = N;
        res.fn[l] = (float)N;
    }

    // ws layout: cnt 256KB + ovf_cnt 4B @0 | ovf 8MB @1MiB | slots 80MB @16MiB
    const size_t WS_NEED = (16u << 20) + (size_t)NBKT * CAP * 16;

    if (ws_size >= WS_NEED) {
        char* w = (char*)d_ws;
        unsigned* cnt     = (unsigned*)(w);
        unsigned* ovf_cnt = (unsigned*)(w + NBKT * 4);
        unsigned* ovf     = (unsigned*)(w + (1u << 20));
        f32x4*    slots   = (f32x4*)   (w + (16u << 20));

        hipMemsetAsync(cnt, 0, NBKT * 4 + 4, stream);
        bucket_kernel<<<NPOINTS / 256, 256, 0, stream>>>(xy, cnt, slots, ovf_cnt, ovf);
        main_kernel  <<<NBKT / 4,      256, 0, stream>>>(cnt, slots, tables, out, res);
        ovf_kernel   <<<16,            256, 0, stream>>>(ovf_cnt, ovf, xy, tables, out, res);
    } else {
        hashgrid2d_fallback<<<NPOINTS / 256, 256, 0, stream>>>(xy, tables, out, res);
    }
}